// Round 3
// baseline (120.511 us; speedup 1.0000x reference)
//
#include <hip/hip_runtime.h>
#include <math.h>

#define NL    4096      // coarse points
#define NH    16384     // fine points
#define NF4   64        // 256 features / 4
#define BLK   1024      // threads per block (16 waves)
#define NW    16        // waves per block
#define FPB   64        // fine points per block (lane = fine point)
#define PERW  (NL / NW) // 256 candidates per wave

// Sorted top-3 insert: min/med3 for values, 3 cmps + 5 cndmasks for indices.
// Strict < keeps earliest index on ties (candidates arrive in ascending index
// order within a set) — matches jax.lax.top_k stability.
__device__ __forceinline__ void ins3(float d, int j,
    float& b0, float& b1, float& b2, int& i0, int& i1, int& i2)
{
  const bool p0 = d < b0;
  const bool p1 = d < b1;
  const bool p2 = d < b2;
  const int ni0 = p0 ? j : i0;
  const int ni1 = p0 ? i0 : (p1 ? j : i1);
  const int ni2 = p1 ? i1 : (p2 ? j : i2);
  const float nb0 = fminf(b0, d);
  const float nb1 = __builtin_amdgcn_fmed3f(d, b0, b1);
  const float nb2 = __builtin_amdgcn_fmed3f(d, b1, b2);
  b0 = nb0; b1 = nb1; b2 = nb2;
  i0 = ni0; i1 = ni1; i2 = ni2;
}

// Lexicographic (d, j) insert — merging lists whose index order is arbitrary.
__device__ __forceinline__ void lexins3(float d, int j,
    float& b0, float& b1, float& b2, int& i0, int& i1, int& i2)
{
  bool s2 = (d < b2) || ((d == b2) && (j < i2));
  b2 = s2 ? d : b2;  i2 = s2 ? j : i2;
  bool s1 = (b2 < b1) || ((b2 == b1) && (i2 < i1));
  float tf = b1; int ti = i1;
  b1 = s1 ? b2 : b1;  i1 = s1 ? i2 : i1;
  b2 = s1 ? tf : b2;  i2 = s1 ? ti : i2;
  bool s0 = (b1 < b0) || ((b1 == b0) && (i1 < i0));
  tf = b0; ti = i0;
  b0 = s0 ? b1 : b0;  i0 = s0 ? i1 : i0;
  b1 = s0 ? tf : b1;  i1 = s0 ? ti : i1;
}

// Prologue: pack coarse points as (x,y,z,|l|^2) into d_ws. |l|^2 uses the
// EXACT np rounding sequence: (l0*l0 + l1*l1) + l2*l2, no contraction.
__global__ __launch_bounds__(256)
void prep_kernel(const float* __restrict__ pos_l, float4* __restrict__ cand)
{
  const int i = blockIdx.x * 256 + threadIdx.x;   // 0..NL-1
  const float l0 = pos_l[i * 3 + 0];
  const float l1 = pos_l[i * 3 + 1];
  const float l2 = pos_l[i * 3 + 2];
  const float ll = __fadd_rn(__fadd_rn(__fmul_rn(l0, l0), __fmul_rn(l1, l1)),
                             __fmul_rn(l2, l2));
  cand[i] = make_float4(l0, l1, l2, ll);
}

__global__ __launch_bounds__(BLK)
void knn_interp_kernel(const float* __restrict__ x,
                       const float* __restrict__ pos_l,
                       const float* __restrict__ pos_h,
                       const float4* __restrict__ cand,   // d_ws: (x,y,z,ll)
                       float* __restrict__ out)
{
  __shared__ float  pd[NW * FPB * 3];     // per-wave partial top-3 dists 12 KB
  __shared__ int    pj[NW * FPB * 3];     // per-wave partial top-3 idx   12 KB
  __shared__ float  wn[FPB * 3];          // normalized weights
  __shared__ int    sj[FPB * 3];          // selected neighbor idx

  const int tid  = threadIdx.x;
  const int lane = tid & 63;
  const int wv   = __builtin_amdgcn_readfirstlane(tid >> 6);   // wave id 0..15
  const int fg   = blockIdx.x * FPB + lane;                    // fine point

  // |h|^2 with np rounding: (h0*h0 + h1*h1) + h2*h2, no contraction
  const float h0 = pos_h[fg * 3 + 0];
  const float h1 = pos_h[fg * 3 + 1];
  const float h2 = pos_h[fg * 3 + 2];
  const float hh = __fadd_rn(__fadd_rn(__fmul_rn(h0, h0), __fmul_rn(h1, h1)),
                             __fmul_rn(h2, h2));

  // two independent top-3 accumulator sets (even / odd candidates) for ILP
  float a0 = INFINITY, a1 = INFINITY, a2 = INFINITY;  int ai0 = 0, ai1 = 0, ai2 = 0;
  float c0 = INFINITY, c1 = INFINITY, c2 = INFINITY;  int ci0 = 0, ci1 = 0, ci2 = 0;

  // wave-uniform candidate slice: scalar (SGPR) loads, no LDS, no VMEM in loop
  const int jbase = __builtin_amdgcn_readfirstlane(wv * PERW);

  #pragma unroll 8
  for (int t = 0; t < PERW; t += 2) {
    const float4 pa = cand[jbase + t];
    const float4 pb = cand[jbase + t + 1];
    // d2 = (hh - 2*dot) + ll — EXACT rounding sequence of the passing kernel
    const float dota = __fmaf_rn(h2, pa.z, __fmaf_rn(h1, pa.y, __fmul_rn(h0, pa.x)));
    const float da   = __fadd_rn(__fsub_rn(hh, __fmul_rn(2.0f, dota)), pa.w);
    const float dotb = __fmaf_rn(h2, pb.z, __fmaf_rn(h1, pb.y, __fmul_rn(h0, pb.x)));
    const float db   = __fadd_rn(__fsub_rn(hh, __fmul_rn(2.0f, dotb)), pb.w);
    ins3(da, jbase + t,     a0, a1, a2, ai0, ai1, ai2);
    ins3(db, jbase + t + 1, c0, c1, c2, ci0, ci1, ci2);
  }

  // merge odd-set into even-set (index order arbitrary between sets -> lex)
  lexins3(c0, ci0, a0, a1, a2, ai0, ai1, ai2);
  lexins3(c1, ci1, a0, a1, a2, ai0, ai1, ai2);
  lexins3(c2, ci2, a0, a1, a2, ai0, ai1, ai2);

  {
    const int s = (wv * FPB + lane) * 3;
    pd[s + 0] = a0; pd[s + 1] = a1; pd[s + 2] = a2;
    pj[s + 0] = ai0; pj[s + 1] = ai1; pj[s + 2] = ai2;
  }
  __syncthreads();

  // first 64 threads: merge NW partial lists per fine point, compute weights
  if (tid < FPB) {
    float b0 = INFINITY, b1 = INFINITY, b2 = INFINITY;
    int   i0 = 0x7fffffff, i1 = 0x7fffffff, i2 = 0x7fffffff;
    for (int w = 0; w < NW; ++w) {
      const int s = (w * FPB + tid) * 3;
      lexins3(pd[s + 0], pj[s + 0], b0, b1, b2, i0, i1, i2);
      lexins3(pd[s + 1], pj[s + 1], b0, b1, b2, i0, i1, i2);
      lexins3(pd[s + 2], pj[s + 2], b0, b1, b2, i0, i1, i2);
    }

    const int fm = blockIdx.x * FPB + tid;
    const float H0 = pos_h[fm * 3 + 0];
    const float H1 = pos_h[fm * 3 + 1];
    const float H2 = pos_h[fm * 3 + 2];

    float wk[3];
    int   jk[3] = { i0, i1, i2 };
    #pragma unroll
    for (int k = 0; k < 3; ++k) {
      const int j = jk[k];
      // exact recompute per reference: diff, squares, sequential sum (no fma)
      const float dx = __fsub_rn(H0, pos_l[j * 3 + 0]);
      const float dy = __fsub_rn(H1, pos_l[j * 3 + 1]);
      const float dz = __fsub_rn(H2, pos_l[j * 3 + 2]);
      float d2 = __fadd_rn(__fadd_rn(__fmul_rn(dx, dx), __fmul_rn(dy, dy)),
                           __fmul_rn(dz, dz));
      d2 = fmaxf(d2, 1e-16f);              // clip(d2, EPS)
      wk[k] = __frcp_rn(d2);               // 1/d2
    }
    const float W  = __fadd_rn(__fadd_rn(wk[0], wk[1]), wk[2]);
    const float rW = __frcp_rn(W);
    #pragma unroll
    for (int k = 0; k < 3; ++k) {
      wn[tid * 3 + k] = wk[k] * rW;        // pre-normalized weights
      sj[tid * 3 + k] = jk[k];
    }
  }
  __syncthreads();

  // interpolation: 64 fine x 64 float4 = 4096 tasks per block, 4 per thread
  const float4* __restrict__ x4   = (const float4*)x;
  float4* __restrict__       out4 = (float4*)out;
  #pragma unroll
  for (int i = 0; i < (FPB * NF4) / BLK; ++i) {
    const int task = tid + i * BLK;
    const int f    = task >> 6;         // local fine point
    const int cc   = task & 63;         // float4 column
    const int j0 = sj[f * 3 + 0], j1 = sj[f * 3 + 1], j2 = sj[f * 3 + 2];
    const float w0 = wn[f * 3 + 0], w1 = wn[f * 3 + 1], w2 = wn[f * 3 + 2];
    const float4 xa = x4[j0 * NF4 + cc];
    const float4 xb = x4[j1 * NF4 + cc];
    const float4 xc = x4[j2 * NF4 + cc];
    float4 r;
    r.x = xa.x * w0 + xb.x * w1 + xc.x * w2;
    r.y = xa.y * w0 + xb.y * w1 + xc.y * w2;
    r.z = xa.z * w0 + xb.z * w1 + xc.z * w2;
    r.w = xa.w * w0 + xb.w * w1 + xc.w * w2;
    out4[(blockIdx.x * FPB + f) * NF4 + cc] = r;
  }
}

extern "C" void kernel_launch(void* const* d_in, const int* in_sizes, int n_in,
                              void* d_out, int out_size, void* d_ws, size_t ws_size,
                              hipStream_t stream)
{
  const float* x     = (const float*)d_in[0];   // [4096, 256]
  const float* pos_l = (const float*)d_in[1];   // [4096, 3]
  const float* pos_h = (const float*)d_in[2];   // [16384, 3]
  float* out = (float*)d_out;                   // [16384, 256]
  float4* cand = (float4*)d_ws;                 // 4096 * 16 B = 64 KB scratch

  hipLaunchKernelGGL(prep_kernel, dim3(NL / 256), dim3(256), 0, stream,
                     pos_l, cand);
  hipLaunchKernelGGL(knn_interp_kernel, dim3(NH / FPB), dim3(BLK), 0, stream,
                     x, pos_l, pos_h, cand, out);
}

// Round 4
// 110.515 us; speedup vs baseline: 1.0904x; 1.0904x over previous
//
#include <hip/hip_runtime.h>
#include <math.h>

#define NL    4096      // coarse points
#define NH    16384     // fine points
#define NF4   64        // 256 features / 4
#define BLK   1024      // threads per block (16 waves)
#define NW    16        // waves per block
#define FPB   64        // fine points per block (lane = fine point)
#define PERW  (NL / NW) // 256 candidates per wave
#define CHUNK 8         // candidates per scalar-load chunk (2 x s_load_dwordx16)

typedef float v16f __attribute__((ext_vector_type(16)));

// Sorted top-3 insert: min/med3 for values, 3 cmps + 5 cndmasks for indices.
// Strict < keeps earliest index on ties (candidates arrive in ascending index
// order within a set) — matches jax.lax.top_k stability.
__device__ __forceinline__ void ins3(float d, int j,
    float& b0, float& b1, float& b2, int& i0, int& i1, int& i2)
{
  const bool p0 = d < b0;
  const bool p1 = d < b1;
  const bool p2 = d < b2;
  const int ni0 = p0 ? j : i0;
  const int ni1 = p0 ? i0 : (p1 ? j : i1);
  const int ni2 = p1 ? i1 : (p2 ? j : i2);
  const float nb0 = fminf(b0, d);
  const float nb1 = __builtin_amdgcn_fmed3f(d, b0, b1);
  const float nb2 = __builtin_amdgcn_fmed3f(d, b1, b2);
  b0 = nb0; b1 = nb1; b2 = nb2;
  i0 = ni0; i1 = ni1; i2 = ni2;
}

// Lexicographic (d, j) insert — merging lists whose index order is arbitrary.
__device__ __forceinline__ void lexins3(float d, int j,
    float& b0, float& b1, float& b2, int& i0, int& i1, int& i2)
{
  bool s2 = (d < b2) || ((d == b2) && (j < i2));
  b2 = s2 ? d : b2;  i2 = s2 ? j : i2;
  bool s1 = (b2 < b1) || ((b2 == b1) && (i2 < i1));
  float tf = b1; int ti = i1;
  b1 = s1 ? b2 : b1;  i1 = s1 ? i2 : i1;
  b2 = s1 ? tf : b2;  i2 = s1 ? ti : i2;
  bool s0 = (b1 < b0) || ((b1 == b0) && (i1 < i0));
  tf = b0; ti = i0;
  b0 = s0 ? b1 : b0;  i0 = s0 ? i1 : i0;
  b1 = s0 ? tf : b1;  i1 = s0 ? ti : i1;
}

// Prologue: pack coarse points as (x,y,z,|l|^2) into d_ws. |l|^2 uses the
// EXACT np rounding sequence: (l0*l0 + l1*l1) + l2*l2, no contraction.
__global__ __launch_bounds__(256)
void prep_kernel(const float* __restrict__ pos_l, float4* __restrict__ cand)
{
  const int i = blockIdx.x * 256 + threadIdx.x;   // 0..NL-1
  const float l0 = pos_l[i * 3 + 0];
  const float l1 = pos_l[i * 3 + 1];
  const float l2 = pos_l[i * 3 + 2];
  const float ll = __fadd_rn(__fadd_rn(__fmul_rn(l0, l0), __fmul_rn(l1, l1)),
                             __fmul_rn(l2, l2));
  cand[i] = make_float4(l0, l1, l2, ll);
}

__global__ __launch_bounds__(BLK)
void knn_interp_kernel(const float* __restrict__ x,
                       const float* __restrict__ pos_l,
                       const float* __restrict__ pos_h,
                       const float* __restrict__ cand,   // d_ws: (x,y,z,ll)*NL
                       float* __restrict__ out)
{
  __shared__ float  pd[NW * FPB * 3];     // per-wave partial top-3 dists 12 KB
  __shared__ int    pj[NW * FPB * 3];     // per-wave partial top-3 idx   12 KB
  __shared__ float  wn[FPB * 3];          // normalized weights
  __shared__ int    sj[FPB * 3];          // selected neighbor idx

  const int tid  = threadIdx.x;
  const int lane = tid & 63;
  const int wv   = __builtin_amdgcn_readfirstlane(tid >> 6);   // wave id 0..15
  const int fg   = blockIdx.x * FPB + lane;                    // fine point

  // |h|^2 with np rounding: (h0*h0 + h1*h1) + h2*h2, no contraction
  const float h0 = pos_h[fg * 3 + 0];
  const float h1 = pos_h[fg * 3 + 1];
  const float h2 = pos_h[fg * 3 + 2];
  const float hh = __fadd_rn(__fadd_rn(__fmul_rn(h0, h0), __fmul_rn(h1, h1)),
                             __fmul_rn(h2, h2));

  // two independent top-3 accumulator sets for ILP (a: chunk pos 0-3, c: 4-7;
  // both see ascending candidate indices)
  float a0 = INFINITY, a1 = INFINITY, a2 = INFINITY;  int ai0 = 0, ai1 = 0, ai2 = 0;
  float c0 = INFINITY, c1 = INFINITY, c2 = INFINITY;  int ci0 = 0, ci1 = 0, ci2 = 0;

  // wave-uniform candidate slice: forced scalar (SMEM) loads, no LDS, no VMEM
  const int jbase = __builtin_amdgcn_readfirstlane(wv * PERW);

  for (int t = 0; t < PERW; t += CHUNK) {
    // 8 candidates = 128 B via two s_load_dwordx16 on the scalar pipe.
    // SMEM returns may be out of order -> single lgkmcnt(0) for both.
    v16f sA, sB;
    const float* p = cand + (size_t)(jbase + t) * 4;   // uniform address
    asm volatile("s_load_dwordx16 %0, %2, 0x0\n\t"
                 "s_load_dwordx16 %1, %2, 0x40\n\t"
                 "s_waitcnt lgkmcnt(0)"
                 : "=&s"(sA), "=&s"(sB) : "s"(p) : "memory");

    #pragma unroll
    for (int i = 0; i < 4; ++i) {
      const float lx = sA[i * 4 + 0], ly = sA[i * 4 + 1];
      const float lz = sA[i * 4 + 2], lw = sA[i * 4 + 3];
      // d2 = (hh - 2*dot) + ll — EXACT rounding sequence of the passing kernel
      const float dot = __fmaf_rn(h2, lz, __fmaf_rn(h1, ly, __fmul_rn(h0, lx)));
      const float d   = __fadd_rn(__fsub_rn(hh, __fmul_rn(2.0f, dot)), lw);
      ins3(d, jbase + t + i, a0, a1, a2, ai0, ai1, ai2);
    }
    #pragma unroll
    for (int i = 0; i < 4; ++i) {
      const float lx = sB[i * 4 + 0], ly = sB[i * 4 + 1];
      const float lz = sB[i * 4 + 2], lw = sB[i * 4 + 3];
      const float dot = __fmaf_rn(h2, lz, __fmaf_rn(h1, ly, __fmul_rn(h0, lx)));
      const float d   = __fadd_rn(__fsub_rn(hh, __fmul_rn(2.0f, dot)), lw);
      ins3(d, jbase + t + 4 + i, c0, c1, c2, ci0, ci1, ci2);
    }
  }

  // merge set c into set a (index order arbitrary between sets -> lex)
  lexins3(c0, ci0, a0, a1, a2, ai0, ai1, ai2);
  lexins3(c1, ci1, a0, a1, a2, ai0, ai1, ai2);
  lexins3(c2, ci2, a0, a1, a2, ai0, ai1, ai2);

  {
    const int s = (wv * FPB + lane) * 3;
    pd[s + 0] = a0; pd[s + 1] = a1; pd[s + 2] = a2;
    pj[s + 0] = ai0; pj[s + 1] = ai1; pj[s + 2] = ai2;
  }
  __syncthreads();

  // first 64 threads: merge NW partial lists per fine point, compute weights
  if (tid < FPB) {
    float b0 = INFINITY, b1 = INFINITY, b2 = INFINITY;
    int   i0 = 0x7fffffff, i1 = 0x7fffffff, i2 = 0x7fffffff;
    for (int w = 0; w < NW; ++w) {
      const int s = (w * FPB + tid) * 3;
      lexins3(pd[s + 0], pj[s + 0], b0, b1, b2, i0, i1, i2);
      lexins3(pd[s + 1], pj[s + 1], b0, b1, b2, i0, i1, i2);
      lexins3(pd[s + 2], pj[s + 2], b0, b1, b2, i0, i1, i2);
    }

    const int fm = blockIdx.x * FPB + tid;
    const float H0 = pos_h[fm * 3 + 0];
    const float H1 = pos_h[fm * 3 + 1];
    const float H2 = pos_h[fm * 3 + 2];

    float wk[3];
    int   jk[3] = { i0, i1, i2 };
    #pragma unroll
    for (int k = 0; k < 3; ++k) {
      const int j = jk[k];
      // exact recompute per reference: diff, squares, sequential sum (no fma)
      const float dx = __fsub_rn(H0, pos_l[j * 3 + 0]);
      const float dy = __fsub_rn(H1, pos_l[j * 3 + 1]);
      const float dz = __fsub_rn(H2, pos_l[j * 3 + 2]);
      float d2 = __fadd_rn(__fadd_rn(__fmul_rn(dx, dx), __fmul_rn(dy, dy)),
                           __fmul_rn(dz, dz));
      d2 = fmaxf(d2, 1e-16f);              // clip(d2, EPS)
      wk[k] = __frcp_rn(d2);               // 1/d2
    }
    const float W  = __fadd_rn(__fadd_rn(wk[0], wk[1]), wk[2]);
    const float rW = __frcp_rn(W);
    #pragma unroll
    for (int k = 0; k < 3; ++k) {
      wn[tid * 3 + k] = wk[k] * rW;        // pre-normalized weights
      sj[tid * 3 + k] = jk[k];
    }
  }
  __syncthreads();

  // interpolation: 64 fine x 64 float4 = 4096 tasks per block, 4 per thread
  const float4* __restrict__ x4   = (const float4*)x;
  float4* __restrict__       out4 = (float4*)out;
  #pragma unroll
  for (int i = 0; i < (FPB * NF4) / BLK; ++i) {
    const int task = tid + i * BLK;
    const int f    = task >> 6;         // local fine point
    const int cc   = task & 63;         // float4 column
    const int j0 = sj[f * 3 + 0], j1 = sj[f * 3 + 1], j2 = sj[f * 3 + 2];
    const float w0 = wn[f * 3 + 0], w1 = wn[f * 3 + 1], w2 = wn[f * 3 + 2];
    const float4 xa = x4[j0 * NF4 + cc];
    const float4 xb = x4[j1 * NF4 + cc];
    const float4 xc = x4[j2 * NF4 + cc];
    float4 r;
    r.x = xa.x * w0 + xb.x * w1 + xc.x * w2;
    r.y = xa.y * w0 + xb.y * w1 + xc.y * w2;
    r.z = xa.z * w0 + xb.z * w1 + xc.z * w2;
    r.w = xa.w * w0 + xb.w * w1 + xc.w * w2;
    out4[(blockIdx.x * FPB + f) * NF4 + cc] = r;
  }
}

extern "C" void kernel_launch(void* const* d_in, const int* in_sizes, int n_in,
                              void* d_out, int out_size, void* d_ws, size_t ws_size,
                              hipStream_t stream)
{
  const float* x     = (const float*)d_in[0];   // [4096, 256]
  const float* pos_l = (const float*)d_in[1];   // [4096, 3]
  const float* pos_h = (const float*)d_in[2];   // [16384, 3]
  float* out = (float*)d_out;                   // [16384, 256]
  float* cand = (float*)d_ws;                   // 4096 * 16 B = 64 KB scratch

  hipLaunchKernelGGL(prep_kernel, dim3(NL / 256), dim3(256), 0, stream,
                     pos_l, (float4*)cand);
  hipLaunchKernelGGL(knn_interp_kernel, dim3(NH / FPB), dim3(BLK), 0, stream,
                     x, pos_l, pos_h, cand, out);
}

// Round 5
// 108.765 us; speedup vs baseline: 1.1080x; 1.0161x over previous
//
#include <hip/hip_runtime.h>
#include <math.h>

#define NL    4096      // coarse points
#define NH    16384     // fine points
#define NF4   64        // 256 features / 4
#define BLK   1024      // threads per block (16 waves)
#define NW    16        // waves per block
#define FPB   64        // fine points per block (lane = fine point)
#define PERW  (NL / NW) // 256 candidates per wave
#define BATCH 16        // candidates per scalar-load batch (4 x s_load_dwordx16)

typedef float v16f __attribute__((ext_vector_type(16)));

// Sorted top-3 insert: min/med3 for values, 3 cmps + 5 cndmasks for indices.
// Strict < keeps earliest index on ties (candidates arrive in ascending index
// order within a set) — matches jax.lax.top_k stability.
__device__ __forceinline__ void ins3(float d, int j,
    float& b0, float& b1, float& b2, int& i0, int& i1, int& i2)
{
  const bool p0 = d < b0;
  const bool p1 = d < b1;
  const bool p2 = d < b2;
  const int ni0 = p0 ? j : i0;
  const int ni1 = p0 ? i0 : (p1 ? j : i1);
  const int ni2 = p1 ? i1 : (p2 ? j : i2);
  const float nb0 = fminf(b0, d);
  const float nb1 = __builtin_amdgcn_fmed3f(d, b0, b1);
  const float nb2 = __builtin_amdgcn_fmed3f(d, b1, b2);
  b0 = nb0; b1 = nb1; b2 = nb2;
  i0 = ni0; i1 = ni1; i2 = ni2;
}

// Lexicographic (d, j) insert — merging lists whose index order is arbitrary.
__device__ __forceinline__ void lexins3(float d, int j,
    float& b0, float& b1, float& b2, int& i0, int& i1, int& i2)
{
  bool s2 = (d < b2) || ((d == b2) && (j < i2));
  b2 = s2 ? d : b2;  i2 = s2 ? j : i2;
  bool s1 = (b2 < b1) || ((b2 == b1) && (i2 < i1));
  float tf = b1; int ti = i1;
  b1 = s1 ? b2 : b1;  i1 = s1 ? i2 : i1;
  b2 = s1 ? tf : b2;  i2 = s1 ? ti : i2;
  bool s0 = (b1 < b0) || ((b1 == b0) && (i1 < i0));
  tf = b0; ti = i0;
  b0 = s0 ? b1 : b0;  i0 = s0 ? i1 : i0;
  b1 = s0 ? tf : b1;  i1 = s0 ? ti : i1;
}

// Evaluate 4 candidates held in one v16f (4 x float4: x,y,z,ll), ascending j.
// Distance rounding sequence is EXACTLY the round-1 passing kernel's.
__device__ __forceinline__ void eval4(const v16f& s, int jb, const float h0,
    const float h1, const float h2, const float hh,
    float& b0, float& b1, float& b2, int& i0, int& i1, int& i2)
{
  #pragma unroll
  for (int i = 0; i < 4; ++i) {
    const float lx = s[i * 4 + 0], ly = s[i * 4 + 1];
    const float lz = s[i * 4 + 2], lw = s[i * 4 + 3];
    const float dot = __fmaf_rn(h2, lz, __fmaf_rn(h1, ly, __fmul_rn(h0, lx)));
    const float d   = __fadd_rn(__fsub_rn(hh, __fmul_rn(2.0f, dot)), lw);
    ins3(d, jb + i, b0, b1, b2, i0, i1, i2);
  }
}

// Prologue: pack coarse points as (x,y,z,|l|^2) into d_ws. |l|^2 uses the
// EXACT np rounding sequence: (l0*l0 + l1*l1) + l2*l2, no contraction.
__global__ __launch_bounds__(256)
void prep_kernel(const float* __restrict__ pos_l, float4* __restrict__ cand)
{
  const int i = blockIdx.x * 256 + threadIdx.x;   // 0..NL-1
  const float l0 = pos_l[i * 3 + 0];
  const float l1 = pos_l[i * 3 + 1];
  const float l2 = pos_l[i * 3 + 2];
  const float ll = __fadd_rn(__fadd_rn(__fmul_rn(l0, l0), __fmul_rn(l1, l1)),
                             __fmul_rn(l2, l2));
  cand[i] = make_float4(l0, l1, l2, ll);
}

__global__ __launch_bounds__(BLK)
void knn_interp_kernel(const float* __restrict__ x,
                       const float* __restrict__ pos_l,
                       const float* __restrict__ pos_h,
                       const float* __restrict__ cand,   // d_ws: (x,y,z,ll)*NL
                       float* __restrict__ out)
{
  __shared__ float  pd[NW * FPB * 3];     // per-wave partial top-3 dists 12 KB
  __shared__ int    pj[NW * FPB * 3];     // per-wave partial top-3 idx   12 KB
  __shared__ float  wn[FPB * 3];          // normalized weights
  __shared__ int    sj[FPB * 3];          // selected neighbor idx

  const int tid  = threadIdx.x;
  const int lane = tid & 63;
  const int wv   = __builtin_amdgcn_readfirstlane(tid >> 6);   // wave id 0..15
  const int fg   = blockIdx.x * FPB + lane;                    // fine point

  // |h|^2 with np rounding: (h0*h0 + h1*h1) + h2*h2, no contraction
  const float h0 = pos_h[fg * 3 + 0];
  const float h1 = pos_h[fg * 3 + 1];
  const float h2 = pos_h[fg * 3 + 2];
  const float hh = __fadd_rn(__fadd_rn(__fmul_rn(h0, h0), __fmul_rn(h1, h1)),
                             __fmul_rn(h2, h2));

  // two independent top-3 accumulator sets for ILP (a: batch pos 0-7, c: 8-15;
  // each sees ascending candidate indices across batches)
  float a0 = INFINITY, a1 = INFINITY, a2 = INFINITY;  int ai0 = 0, ai1 = 0, ai2 = 0;
  float c0 = INFINITY, c1 = INFINITY, c2 = INFINITY;  int ci0 = 0, ci1 = 0, ci2 = 0;

  // wave-uniform candidate slice: forced scalar (SMEM) loads, no LDS, no VMEM
  const int jbase = __builtin_amdgcn_readfirstlane(wv * PERW);

  for (int t = 0; t < PERW; t += BATCH) {
    // 16 candidates = 256 B via four s_load_dwordx16 on the scalar pipe,
    // ONE wait per batch (SMEM returns can be OOO -> must wait lgkmcnt(0);
    // batching amortizes the K$ latency over 272 VALU instructions).
    v16f sA, sB, sC, sD;
    const float* p = cand + (size_t)(jbase + t) * 4;   // uniform address
    asm volatile("s_load_dwordx16 %0, %4, 0x0\n\t"
                 "s_load_dwordx16 %1, %4, 0x40\n\t"
                 "s_load_dwordx16 %2, %4, 0x80\n\t"
                 "s_load_dwordx16 %3, %4, 0xc0"
                 : "=&s"(sA), "=&s"(sB), "=&s"(sC), "=&s"(sD)
                 : "s"(p));
    // Tie the wait to the loaded values so no use can be scheduled above it.
    asm volatile("s_waitcnt lgkmcnt(0)"
                 : "+s"(sA), "+s"(sB), "+s"(sC), "+s"(sD));

    eval4(sA, jbase + t +  0, h0, h1, h2, hh, a0, a1, a2, ai0, ai1, ai2);
    eval4(sB, jbase + t +  4, h0, h1, h2, hh, a0, a1, a2, ai0, ai1, ai2);
    eval4(sC, jbase + t +  8, h0, h1, h2, hh, c0, c1, c2, ci0, ci1, ci2);
    eval4(sD, jbase + t + 12, h0, h1, h2, hh, c0, c1, c2, ci0, ci1, ci2);
  }

  // merge set c into set a (index order arbitrary between sets -> lex)
  lexins3(c0, ci0, a0, a1, a2, ai0, ai1, ai2);
  lexins3(c1, ci1, a0, a1, a2, ai0, ai1, ai2);
  lexins3(c2, ci2, a0, a1, a2, ai0, ai1, ai2);

  {
    const int s = (wv * FPB + lane) * 3;
    pd[s + 0] = a0; pd[s + 1] = a1; pd[s + 2] = a2;
    pj[s + 0] = ai0; pj[s + 1] = ai1; pj[s + 2] = ai2;
  }
  __syncthreads();

  // first 64 threads: merge NW partial lists per fine point, compute weights
  if (tid < FPB) {
    float b0 = INFINITY, b1 = INFINITY, b2 = INFINITY;
    int   i0 = 0x7fffffff, i1 = 0x7fffffff, i2 = 0x7fffffff;
    for (int w = 0; w < NW; ++w) {
      const int s = (w * FPB + tid) * 3;
      lexins3(pd[s + 0], pj[s + 0], b0, b1, b2, i0, i1, i2);
      lexins3(pd[s + 1], pj[s + 1], b0, b1, b2, i0, i1, i2);
      lexins3(pd[s + 2], pj[s + 2], b0, b1, b2, i0, i1, i2);
    }

    const int fm = blockIdx.x * FPB + tid;
    const float H0 = pos_h[fm * 3 + 0];
    const float H1 = pos_h[fm * 3 + 1];
    const float H2 = pos_h[fm * 3 + 2];

    float wk[3];
    int   jk[3] = { i0, i1, i2 };
    #pragma unroll
    for (int k = 0; k < 3; ++k) {
      const int j = jk[k];
      // exact recompute per reference: diff, squares, sequential sum (no fma)
      const float dx = __fsub_rn(H0, pos_l[j * 3 + 0]);
      const float dy = __fsub_rn(H1, pos_l[j * 3 + 1]);
      const float dz = __fsub_rn(H2, pos_l[j * 3 + 2]);
      float d2 = __fadd_rn(__fadd_rn(__fmul_rn(dx, dx), __fmul_rn(dy, dy)),
                           __fmul_rn(dz, dz));
      d2 = fmaxf(d2, 1e-16f);              // clip(d2, EPS)
      wk[k] = __frcp_rn(d2);               // 1/d2
    }
    const float W  = __fadd_rn(__fadd_rn(wk[0], wk[1]), wk[2]);
    const float rW = __frcp_rn(W);
    #pragma unroll
    for (int k = 0; k < 3; ++k) {
      wn[tid * 3 + k] = wk[k] * rW;        // pre-normalized weights
      sj[tid * 3 + k] = jk[k];
    }
  }
  __syncthreads();

  // interpolation: 64 fine x 64 float4 = 4096 tasks per block, 4 per thread
  const float4* __restrict__ x4   = (const float4*)x;
  float4* __restrict__       out4 = (float4*)out;
  #pragma unroll
  for (int i = 0; i < (FPB * NF4) / BLK; ++i) {
    const int task = tid + i * BLK;
    const int f    = task >> 6;         // local fine point
    const int cc   = task & 63;         // float4 column
    const int j0 = sj[f * 3 + 0], j1 = sj[f * 3 + 1], j2 = sj[f * 3 + 2];
    const float w0 = wn[f * 3 + 0], w1 = wn[f * 3 + 1], w2 = wn[f * 3 + 2];
    const float4 xa = x4[j0 * NF4 + cc];
    const float4 xb = x4[j1 * NF4 + cc];
    const float4 xc = x4[j2 * NF4 + cc];
    float4 r;
    r.x = xa.x * w0 + xb.x * w1 + xc.x * w2;
    r.y = xa.y * w0 + xb.y * w1 + xc.y * w2;
    r.z = xa.z * w0 + xb.z * w1 + xc.z * w2;
    r.w = xa.w * w0 + xb.w * w1 + xc.w * w2;
    out4[(blockIdx.x * FPB + f) * NF4 + cc] = r;
  }
}

extern "C" void kernel_launch(void* const* d_in, const int* in_sizes, int n_in,
                              void* d_out, int out_size, void* d_ws, size_t ws_size,
                              hipStream_t stream)
{
  const float* x     = (const float*)d_in[0];   // [4096, 256]
  const float* pos_l = (const float*)d_in[1];   // [4096, 3]
  const float* pos_h = (const float*)d_in[2];   // [16384, 3]
  float* out = (float*)d_out;                   // [16384, 256]
  float* cand = (float*)d_ws;                   // 4096 * 16 B = 64 KB scratch

  hipLaunchKernelGGL(prep_kernel, dim3(NL / 256), dim3(256), 0, stream,
                     pos_l, (float4*)cand);
  hipLaunchKernelGGL(knn_interp_kernel, dim3(NH / FPB), dim3(BLK), 0, stream,
                     x, pos_l, pos_h, cand, out);
}